// Round 4
// baseline (234.371 us; speedup 1.0000x reference)
//
#include <hip/hip_runtime.h>
#include <hip/hip_bf16.h>
#include <stdint.h>

typedef __hip_bfloat16 bf16;
typedef __attribute__((ext_vector_type(8))) short short8;
typedef __attribute__((ext_vector_type(4))) float float4v;
typedef __attribute__((ext_vector_type(2))) float float2v;

#define NVOCAB 113
#define NPAIR (113 * 113)   // 12769
#define DDIM 128
#define HIDDIM 512
#define CAP 128             // fixed bucket capacity per pair
#define PAIRS_PB 16         // pairs per block
#define ROWS_PB 32          // output rows per block
#define LDSB_CAP 512        // staged batch indices per block

// fp32 weight pool element offsets (only biases actually used now)
#define OFF_B1  145792
#define OFF_B2  211840

// bf16 transposed weight pool wb (element offsets)
#define BOFF_WOT 0                         // WOT[d][hk] = W_O[hk][d]     128x128
#define BOFF_W1T 16384                     // W1T[n][d]  = W1[d][n]       512x128
#define BOFF_W2T (16384 + 65536)           // W2T[d][j]  = W2[j][d]       128x512
#define BOFF_WUP (16384 + 65536 + 65536)   // WUP[v][d]  = W_U[v][d]|0    128x128
#define BTOTAL   (16384 + 65536 + 65536 + 16384)  // 163840

__device__ __forceinline__ uint16_t f2b(float f) {
  bf16 h = __float2bfloat16(f);
  return *(uint16_t*)&h;
}
__device__ __forceinline__ float b2f(uint16_t u) {
  return __uint_as_float(((uint32_t)u) << 16);
}
__device__ __forceinline__ float ldsrc(const void* p, int i, int isb) {
  return isb ? b2f(((const uint16_t*)p)[i]) : ((const float*)p)[i];
}

struct SrcPtrs { const void* p[11]; };
// p[0]=tok p[1]=pos p[2]=WQ p[3]=WK p[4]=WV p[5]=WO p[6]=W1 p[7]=b1 p[8]=W2 p[9]=b2 p[10]=WU

// ---------------- K0: zero cursor + dtype detection ----------------
__global__ void init_kernel(const uint32_t* __restrict__ tok_raw,
                            const uint32_t* __restrict__ x_raw,
                            int* __restrict__ flags,
                            int* __restrict__ cursor) {
  const int idx = blockIdx.x * 256 + threadIdx.x;
  for (int i = idx; i < NPAIR; i += gridDim.x * 256) cursor[i] = 0;
  if (blockIdx.x == 0) {
    __shared__ int cnt_bf16, cnt_xnz;
    if (threadIdx.x == 0) { cnt_bf16 = 0; cnt_xnz = 0; }
    __syncthreads();
    uint32_t u = tok_raw[threadIdx.x];
    int e = (u >> 7) & 0xff;
    if (e >= 100 && e <= 126) atomicAdd(&cnt_bf16, 1);
    uint32_t xv = x_raw[2 * threadIdx.x + 1];
    if (xv != 0u) atomicAdd(&cnt_xnz, 1);
    __syncthreads();
    if (threadIdx.x == 0) {
      flags[0] = (cnt_bf16 >= 128) ? 1 : 0;   // float tensors are bf16
      flags[1] = (cnt_xnz == 0) ? 1 : 0;      // x is int64
    }
  }
}

// ---------------- K1: everything parallel, sources read directly ----------
__global__ void __launch_bounds__(384) build_kernel(
    SrcPtrs sp, const uint32_t* __restrict__ x_raw,
    const int* __restrict__ flags, float* __restrict__ wf,
    float* __restrict__ resid_pre, float* __restrict__ qt,
    float* __restrict__ kt, float* __restrict__ vt,
    uint16_t* __restrict__ wb, int* __restrict__ cursor,
    int* __restrict__ blist, int B) {
  const int tid = threadIdx.x;
  const int blk = blockIdx.x;
  const int isb = flags[0];

  if (blk < 226) {
    // ---- qkv + resid ----
    const int row = blk;
    const int t = row >> 1, p = row & 1;
    __shared__ float r[DDIM];
    if (tid < DDIM) {
      float rv = ldsrc(sp.p[0], t * DDIM + tid, isb) +
                 ldsrc(sp.p[1], p * DDIM + tid, isb);
      r[tid] = rv;
      resid_pre[row * DDIM + tid] = rv;
    }
    __syncthreads();
    const int which = tid >> 7, jj = tid & 127;
    const int h = jj >> 5, j = jj & 31;
    const void* wsrc = sp.p[2 + which];
    const int base = h * 4096 + j;
    float a = 0.f;
    if (isb) {
      const uint16_t* w16 = (const uint16_t*)wsrc;
      #pragma unroll 8
      for (int d = 0; d < 128; ++d)
        a += r[d] * b2f(w16[base + d * 32]);
    } else {
      const float* w32 = (const float*)wsrc;
      #pragma unroll 8
      for (int d = 0; d < 128; ++d)
        a += r[d] * w32[base + d * 32];
    }
    float* outp = (which == 0) ? qt : (which == 1) ? kt : vt;
    outp[row * DDIM + jj] = a;
  } else if (blk < 653) {
    // ---- wb build ----
    const int idx = (blk - 226) * 384 + tid;
    if (idx < BTOTAL) {
      float v;
      if (idx < BOFF_W1T) {                       // WOT[d][c] = W_O[c*128+d]
        int l = idx, d = l >> 7, c = l & 127;
        v = ldsrc(sp.p[5], c * 128 + d, isb);
      } else if (idx < BOFF_W2T) {                // W1T[n][d] = W1[d*512+n]
        int l = idx - BOFF_W1T, n = l >> 7, d = l & 127;
        v = ldsrc(sp.p[6], d * 512 + n, isb);
      } else if (idx < BOFF_WUP) {                // W2T[d][j] = W2[j*128+d]
        int l = idx - BOFF_W2T, d = l >> 9, j = l & 511;
        v = ldsrc(sp.p[8], j * 128 + d, isb);
      } else {                                    // WUP[v][d] = W_U[v*128+d] or 0
        int l = idx - BOFF_WUP, vv = l >> 7, d = l & 127;
        v = (vv < NVOCAB) ? ldsrc(sp.p[10], vv * 128 + d, isb) : 0.f;
      }
      wb[idx] = f2b(v);
    }
  } else if (blk < 655) {
    // ---- biases ----
    const int i = (blk - 653) * 384 + tid;
    if (i < 512) wf[OFF_B1 + i] = ldsrc(sp.p[7], i, isb);
    else if (i < 640) wf[OFF_B2 + (i - 512)] = ldsrc(sp.p[9], i - 512, isb);
  } else {
    // ---- batch scatter into fixed-capacity buckets ----
    const int is64 = flags[1];
    const int nthr = (gridDim.x - 655) * 384;
    for (int b = (blk - 655) * 384 + tid; b < B; b += nthr) {
      int t0, t1;
      if (is64) {
        t0 = (int)x_raw[4 * b];
        t1 = (int)x_raw[4 * b + 2];
      } else {
        t0 = (int)x_raw[2 * b];
        t1 = (int)x_raw[2 * b + 1];
      }
      t0 = min(max(t0, 0), NVOCAB - 1);
      t1 = min(max(t1, 0), NVOCAB - 1);
      const int pair = t0 * NVOCAB + t1;
      int pos = atomicAdd(&cursor[pair], 1);
      if (pos < CAP) blist[pair * CAP + pos] = b;
    }
  }
}

// ---------------- K2: fused MFMA kernel, 16 pairs (32 rows) / block -------
// 512 threads / 8 waves. Per-wave B-operand loads halved vs the 8-pair
// version (40 vs 80 for the same 80 MFMA). Non-temporal output stores keep
// the weight pool L2-resident. Accumulation order per output unchanged.
__global__ void __launch_bounds__(512, 3) pair_mfma_kernel(
    const float* __restrict__ resid_pre, const float* __restrict__ qt,
    const float* __restrict__ kt, const float* __restrict__ vt,
    const float* __restrict__ wf, const uint16_t* __restrict__ wb,
    const int* __restrict__ cursor, const int* __restrict__ blist,
    float* __restrict__ out) {
  __shared__ uint16_t bufH[ROWS_PB * 512];   // 32 KB; later logits overlay
  __shared__ uint16_t bufZ[ROWS_PB * 128];   // 8 KB (Z, then R)
  __shared__ uint16_t bufS[ROWS_PB * 128];   // 8 KB (smid bf16)
  __shared__ float    spat[PAIRS_PB * 16];
  __shared__ int      smeta[PAIRS_PB];       // per-pair counts
  __shared__ int      ldsb[LDSB_CAP];        // staged blist slice, 2 KB

  const int tid = threadIdx.x;
  const int blk = blockIdx.x;
  const int lane = tid & 63;
  const int npar = tid >> 6;            // wave id 0..7
  const int l15 = lane & 15, quad = lane >> 4;

  #define ROW_OF(row_) ({                                        \
    int pr_ = blk * PAIRS_PB + ((row_) >> 1);                    \
    if (pr_ >= NPAIR) pr_ = NPAIR - 1;                           \
    int t0_ = pr_ / NVOCAB, t1_ = pr_ - t0_ * NVOCAB;            \
    ((row_) & 1) ? t1_ * 2 + 1 : t0_ * 2; })

  // ---- top-of-kernel prefetches (ride the prologue latency) ----
  if (tid < PAIRS_PB) {
    const int pr = blk * PAIRS_PB + tid;
    smeta[tid] = (pr < NPAIR) ? min(cursor[pr], CAP) : 0;
  }
  const int nG = npar * 16 + l15;       // N=128 column for GEMM0/2/3
  float rpre[2][4];
  #pragma unroll
  for (int mf = 0; mf < 2; ++mf)
    #pragma unroll
    for (int r = 0; r < 4; ++r)
      rpre[mf][r] = resid_pre[ROW_OF(mf * 16 + quad * 4 + r) * DDIM + nG];
  float bias1v[4];
  #pragma unroll
  for (int ni = 0; ni < 4; ++ni)
    bias1v[ni] = wf[OFF_B1 + (npar + ni * 8) * 16 + l15];
  const float bias2 = wf[OFF_B2 + nG];
  // vt rows for the Z phase: 2 rows x 8 cols
  const int zm = tid >> 4, zc0 = (tid & 15) * 8;
  float4 zv0a, zv0b, zv1a, zv1b;
  {
    const int zr0 = ROW_OF((zm >> 1) * 2);
    const int zr1 = ROW_OF((zm >> 1) * 2 + 1);
    const float4* p0 = (const float4*)(vt + zr0 * DDIM + zc0);
    const float4* p1 = (const float4*)(vt + zr1 * DDIM + zc0);
    zv0a = p0[0]; zv0b = p0[1]; zv1a = p1[0]; zv1b = p1[1];
  }

  // ---- prologue: scores (16 pairs x 16 scores = 256 threads) ----
  if (tid < 256) {
    const int pl = tid >> 4, s = tid & 15;
    const int pair = blk * PAIRS_PB + pl;
    if (pair < NPAIR) {
      const int t0 = pair / NVOCAB, t1 = pair - t0 * NVOCAB;
      const int row0 = t0 * 2, row1 = t1 * 2 + 1;
      const int h = s >> 2, qp = (s >> 1) & 1, spp = s & 1;
      const float4* qrow = (const float4*)(qt + (qp ? row1 : row0) * DDIM + h * 32);
      const float4* krow = (const float4*)(kt + (spp ? row1 : row0) * DDIM + h * 32);
      float acc = 0.f;
      #pragma unroll
      for (int j = 0; j < 8; ++j) {
        float4 qv = qrow[j], kv = krow[j];
        acc += qv.x * kv.x + qv.y * kv.y + qv.z * kv.z + qv.w * kv.w;
      }
      spat[pl * 16 + s] = acc * 0.17677669529663687f;
    } else {
      spat[pl * 16 + s] = 0.f;
    }
  }
  __syncthreads();

  int sPre[PAIRS_PB + 1];
  sPre[0] = 0;
  #pragma unroll
  for (int q = 0; q < PAIRS_PB; ++q) sPre[q + 1] = sPre[q] + smeta[q];
  const int tot = sPre[PAIRS_PB];

  // ---- softmax+blend (tid<128) || blist staging (tid>=128) ----
  if (tid < 128) {
    const int pl = tid >> 3, s = tid & 7;
    const int base = pl * 16 + s * 2;
    float s0 = spat[base], s1 = spat[base + 1];
    float m = fmaxf(s0, s1);
    float e0 = __expf(s0 - m), e1 = __expf(s1 - m);
    float inv = 1.f / (e0 + e1);
    spat[base]     = 0.5f + 0.5f * e0 * inv;
    spat[base + 1] = 0.5f + 0.5f * e1 * inv;
  } else {
    const int cap2 = (tot < LDSB_CAP) ? tot : LDSB_CAP;
    for (int i = tid - 128; i < cap2; i += 384) {
      int q = 0;
      #pragma unroll
      for (int qq = 1; qq < PAIRS_PB; ++qq)
        if (i >= sPre[qq]) q = qq;
      ldsb[i] = blist[(blk * PAIRS_PB + q) * CAP + (i - sPre[q])];
    }
  }
  __syncthreads();

  // ---- Z = pattern-weighted V (prefetched), staged bf16 ----
  {
    const int pl = zm >> 1, qp = zm & 1;
    const int h = zc0 >> 5;
    const float p0 = spat[pl * 16 + h * 4 + qp * 2];
    const float p1 = spat[pl * 16 + h * 4 + qp * 2 + 1];
    float v0[8] = {zv0a.x, zv0a.y, zv0a.z, zv0a.w, zv0b.x, zv0b.y, zv0b.z, zv0b.w};
    float v1[8] = {zv1a.x, zv1a.y, zv1a.z, zv1a.w, zv1b.x, zv1b.y, zv1b.z, zv1b.w};
    short8 pk;
    #pragma unroll
    for (int e = 0; e < 8; ++e)
      pk[e] = (short)f2b(p0 * v0[e] + p1 * v1[e]);
    *(short8*)&bufZ[(zm * 16 + ((zc0 >> 3) ^ (zm & 15))) * 8] = pk;
  }
  __syncthreads();

  float smid[2][4];

  // ---- GEMM0: smid = Z x WOT + resid  (N=128, K=128) ----
  {
    short8 af[2][4];
    #pragma unroll
    for (int mf = 0; mf < 2; ++mf)
      #pragma unroll
      for (int ks = 0; ks < 4; ++ks)
        af[mf][ks] = *(const short8*)&bufZ[((mf * 16 + l15) * 16 +
                                           ((ks * 4 + quad) ^ l15)) * 8];
    short8 bW[4];
    {
      const uint16_t* bp = wb + BOFF_WOT + nG * 128 + quad * 8;
      #pragma unroll
      for (int ks = 0; ks < 4; ++ks)
        bW[ks] = *(const short8*)(bp + ks * 32);
    }
    float4v acc[2] = {{0.f, 0.f, 0.f, 0.f}, {0.f, 0.f, 0.f, 0.f}};
    #pragma unroll
    for (int mf = 0; mf < 2; ++mf)
      #pragma unroll
      for (int ks = 0; ks < 4; ++ks)
        acc[mf] = __builtin_amdgcn_mfma_f32_16x16x32_bf16(af[mf][ks], bW[ks],
                                                          acc[mf], 0, 0, 0);
    #pragma unroll
    for (int mf = 0; mf < 2; ++mf)
      #pragma unroll
      for (int r = 0; r < 4; ++r) {
        const int row = mf * 16 + quad * 4 + r;
        float v = acc[mf][r] + rpre[mf][r];
        smid[mf][r] = v;
        bufS[(row * 16 + ((nG >> 3) ^ (row & 15))) * 8 + (nG & 7)] = f2b(v);
      }
  }
  __syncthreads();

  // ---- GEMM1: H = relu(smid x W1 + b1)  (N=512, K=128) ----
  {
    short8 af[2][4];
    #pragma unroll
    for (int mf = 0; mf < 2; ++mf)
      #pragma unroll
      for (int ks = 0; ks < 4; ++ks)
        af[mf][ks] = *(const short8*)&bufS[((mf * 16 + l15) * 16 +
                                           ((ks * 4 + quad) ^ l15)) * 8];
    #pragma unroll
    for (int half = 0; half < 2; ++half) {
      short8 bW[2][4];
      #pragma unroll
      for (int nj = 0; nj < 2; ++nj) {
        const int ni = half * 2 + nj;
        const int n = (npar + ni * 8) * 16 + l15;
        const uint16_t* bp = wb + BOFF_W1T + n * 128 + quad * 8;
        #pragma unroll
        for (int ks = 0; ks < 4; ++ks)
          bW[nj][ks] = *(const short8*)(bp + ks * 32);
      }
      #pragma unroll
      for (int nj = 0; nj < 2; ++nj) {
        const int ni = half * 2 + nj;
        const int n = (npar + ni * 8) * 16 + l15;
        float4v acc[2] = {{0.f, 0.f, 0.f, 0.f}, {0.f, 0.f, 0.f, 0.f}};
        #pragma unroll
        for (int mf = 0; mf < 2; ++mf)
          #pragma unroll
          for (int ks = 0; ks < 4; ++ks)
            acc[mf] = __builtin_amdgcn_mfma_f32_16x16x32_bf16(
                af[mf][ks], bW[nj][ks], acc[mf], 0, 0, 0);
        const float bias = bias1v[ni];
        #pragma unroll
        for (int mf = 0; mf < 2; ++mf)
          #pragma unroll
          for (int r = 0; r < 4; ++r) {
            const int row = mf * 16 + quad * 4 + r;
            bufH[(row * 64 + ((n >> 3) ^ (row & 15))) * 8 + (n & 7)] =
                f2b(fmaxf(acc[mf][r] + bias, 0.f));
          }
      }
    }
  }
  __syncthreads();

  // ---- GEMM2: R = smid + H x W2 + b2  (N=128, K=512) ----
  {
    const uint16_t* bp = wb + BOFF_W2T + nG * 512 + quad * 8;
    float4v acc0 = {0.f, 0.f, 0.f, 0.f};
    float4v acc1 = {0.f, 0.f, 0.f, 0.f};
    #pragma unroll
    for (int half = 0; half < 2; ++half) {
      short8 bB[8];
      #pragma unroll
      for (int k8 = 0; k8 < 8; ++k8)
        bB[k8] = *(const short8*)(bp + (half * 8 + k8) * 32);
      #pragma unroll
      for (int qtr = 0; qtr < 2; ++qtr) {
        short8 a0[4], a1[4];
        #pragma unroll
        for (int k4 = 0; k4 < 4; ++k4) {
          const int ks = half * 8 + qtr * 4 + k4;
          a0[k4] = *(const short8*)&bufH[(l15 * 64 +
                                         ((ks * 4 + quad) ^ l15)) * 8];
          a1[k4] = *(const short8*)&bufH[((16 + l15) * 64 +
                                         ((ks * 4 + quad) ^ l15)) * 8];
        }
        #pragma unroll
        for (int k4 = 0; k4 < 4; ++k4) {
          acc0 = __builtin_amdgcn_mfma_f32_16x16x32_bf16(
              a0[k4], bB[qtr * 4 + k4], acc0, 0, 0, 0);
          acc1 = __builtin_amdgcn_mfma_f32_16x16x32_bf16(
              a1[k4], bB[qtr * 4 + k4], acc1, 0, 0, 0);
        }
      }
    }
    #pragma unroll
    for (int r = 0; r < 4; ++r) {
      const int row0 = quad * 4 + r;
      const int row1 = 16 + quad * 4 + r;
      bufZ[(row0 * 16 + ((nG >> 3) ^ (row0 & 15))) * 8 + (nG & 7)] =
          f2b(acc0[r] + bias2 + smid[0][r]);
      bufZ[(row1 * 16 + ((nG >> 3) ^ (row1 & 15))) * 8 + (nG & 7)] =
          f2b(acc1[r] + bias2 + smid[1][r]);
    }
  }
  __syncthreads();

  // ---- GEMM3: logits = R x WUP^T  (N=128 padded, K=128) -> LDS ----
  float* lds_log = (float*)bufH;        // bufH dead; overlay 16x226 fp32
  {
    short8 ar[2][4];
    #pragma unroll
    for (int mf = 0; mf < 2; ++mf)
      #pragma unroll
      for (int ks = 0; ks < 4; ++ks)
        ar[mf][ks] = *(const short8*)&bufZ[((mf * 16 + l15) * 16 +
                                           ((ks * 4 + quad) ^ l15)) * 8];
    short8 bW[4];
    {
      const uint16_t* bp = wb + BOFF_WUP + nG * 128 + quad * 8;
      #pragma unroll
      for (int ks = 0; ks < 4; ++ks)
        bW[ks] = *(const short8*)(bp + ks * 32);
    }
    float4v acc[2] = {{0.f, 0.f, 0.f, 0.f}, {0.f, 0.f, 0.f, 0.f}};
    #pragma unroll
    for (int mf = 0; mf < 2; ++mf)
      #pragma unroll
      for (int ks = 0; ks < 4; ++ks)
        acc[mf] = __builtin_amdgcn_mfma_f32_16x16x32_bf16(ar[mf][ks], bW[ks],
                                                          acc[mf], 0, 0, 0);
    if (nG < NVOCAB) {
      #pragma unroll
      for (int mf = 0; mf < 2; ++mf)
        #pragma unroll
        for (int r = 0; r < 4; ++r) {
          const int row = mf * 16 + quad * 4 + r;
          lds_log[(row >> 1) * 226 + (row & 1) * 113 + nG] = acc[mf][r];
        }
    }
  }
  __syncthreads();

  // ---- direct scatter-write of output rows (non-temporal) ----
  {
    const int wid = tid >> 6;
    const float2v* lds2 = (const float2v*)lds_log;
    for (int w = wid; w < tot; w += 8) {
      int pl = 0;
      #pragma unroll
      for (int q = 1; q < PAIRS_PB; ++q)
        if (w >= sPre[q]) pl = q;
      const int b = (w < LDSB_CAP)
                        ? ldsb[w]
                        : blist[(blk * PAIRS_PB + pl) * CAP + (w - sPre[pl])];
      const float2v* src = lds2 + pl * 113;
      float2v* dst = (float2v*)out + (size_t)b * 113;
      __builtin_nontemporal_store(src[lane], dst + lane);
      const int j2 = lane + 64;
      if (j2 < 113) __builtin_nontemporal_store(src[j2], dst + j2);
    }
  }
  #undef ROW_OF
}

extern "C" void kernel_launch(void* const* d_in, const int* in_sizes, int n_in,
                              void* d_out, int out_size, void* d_ws, size_t ws_size,
                              hipStream_t stream) {
  // ws layout (byte offsets)
  int*      flags     = (int*)d_ws;                              // 256 B
  float*    wf        = (float*)((char*)d_ws + 256);             // 905728 B (biases)
  float*    resid_pre = (float*)((char*)d_ws + 905984);
  float*    qt        = (float*)((char*)d_ws + 1021696);
  float*    kt        = (float*)((char*)d_ws + 1137408);
  float*    vt        = (float*)((char*)d_ws + 1253120);
  int*      cursor    = (int*)((char*)d_ws + 1368832);           // 51200 B
  int*      blist     = (int*)((char*)d_ws + 1420288);           // 6537728 B
  uint16_t* wb        = (uint16_t*)((char*)d_ws + 12912016);     // 327680 B

  const int B = in_sizes[0] / 2;

  init_kernel<<<64, 256, 0, stream>>>((const uint32_t*)d_in[1],
                                      (const uint32_t*)d_in[0], flags, cursor);

  SrcPtrs sp;
  for (int i = 0; i < 11; ++i) sp.p[i] = d_in[i + 1];

  // 226 qkv + 427 wb + 2 bias + 342 scatter = 997 blocks
  build_kernel<<<997, 384, 0, stream>>>(
      sp, (const uint32_t*)d_in[0], flags, wf, resid_pre, qt, kt, vt, wb,
      cursor, blist, B);

  const int nblk = (NPAIR + PAIRS_PB - 1) / PAIRS_PB;  // 799
  pair_mfma_kernel<<<nblk, 512, 0, stream>>>(resid_pre, qt, kt, vt, wf, wb,
                                             cursor, blist, (float*)d_out);
}